// Round 18
// baseline (110.111 us; speedup 1.0000x reference)
//
#include <hip/hip_runtime.h>

// VQC, 8 qubits, 256 real fp32 amplitudes. One sample per QUAD (4 lanes).
// j[5:0] = register index (qubits 0..5), j[6]=lane k0 (q6), j[7]=lane k1 (q7).
// History: r13 packed-asm => 100MB scratch spill; r16 scalar (256,2) => spill
// gone but VGPR_Count=88 < live state: allocator targeted ~6 waves/EU on its
// own and AGPR-parked state (accvgpr round-trips = the 2x instr bloat).
// r17 deferred-CNOT67 relabel => WRONG (CNOT(5,6) flips k0 under the relabel,
// corrupting l7 for the bit5=1 half). This round: physical CNOT67 restored;
// amdgpu_waves_per_eu(2,2) caps the occupancy TARGET so the 256-reg budget is
// actually used; weight tangents pinned to SGPRs via readfirstlane.

#define DPP_XOR1   0xB1  // quad_perm [1,0,3,2]
#define DPP_XOR2   0x4E  // quad_perm [2,3,0,1]
#define DPP_CNOT67 0x6C  // quad_perm [0,3,2,1]: lanes with bit0=1 swap across bit1

template<int CTRL>
__device__ __forceinline__ float dppf(float v) {
    return __int_as_float(__builtin_amdgcn_mov_dpp(__float_as_int(v), CTRL, 0xF, 0xF, true));
}

__device__ __forceinline__ float rfl(float v) {
    return __int_as_float(__builtin_amdgcn_readfirstlane(__float_as_int(v)));
}

// sin/cos of theta/2 via hw v_sin/v_cos (revolutions); |theta|<=~5.3 in range
__device__ __forceinline__ void sc_half(float theta, float* s, float* c) {
    const float rev = theta * 0.07957747154594767f;  // (theta/2) / (2*pi)
    *s = __builtin_amdgcn_sinf(rev);
    *c = __builtin_amdgcn_cosf(rev);
}

__global__ void __launch_bounds__(256)
__attribute__((amdgpu_waves_per_eu(2, 2)))
vqc_kernel(const float* __restrict__ x,
           const float* __restrict__ w,
           float* __restrict__ out, int B)
{
    const int tid = blockIdx.x * blockDim.x + threadIdx.x;
    const int k   = tid & 3;        // lane-in-quad: bit0 -> q6, bit1 -> q7
    const int s   = tid >> 2;       // sample index
    if (s >= B) return;

    // ---- per-gate tangents for the 32 variational RYs (lane-uniform weights),
    // pinned to SGPRs via readfirstlane.
    float tl[32];
    float C2;
    {
        float prodc = 1.0f;
        #pragma unroll
        for (int g = 0; g < 32; ++g) {
            float sv, cv; sc_half(w[g], &sv, &cv);
            tl[g] = rfl(__fdividef(sv, cv));
            prodc *= cv;
        }
        C2 = rfl(prodc * prodc);    // fold all cos factors into final <Z>
    }

    // ---- encode: H+RY(x) on |0> is a product state: u(0)=(c-s), u(1)=(c+s), /sqrt2 each
    const float4 x0 = *(const float4*)(x + s * 8);
    const float4 x1 = *(const float4*)(x + s * 8 + 4);
    const float ang[8] = {x0.x, x0.y, x0.z, x0.w, x1.x, x1.y, x1.z, x1.w};
    float u0[8], u1[8];
    #pragma unroll
    for (int q = 0; q < 8; ++q) {
        float sv, cv; sc_half(ang[q], &sv, &cv);
        u0[q] = cv - sv; u1[q] = cv + sv;
    }
    const float fl = 0.0625f * ((k & 1) ? u1[6] : u0[6]) * ((k & 2) ? u1[7] : u0[7]);

    // product tree over register qubits 0..5 -> a[64]
    float a[64];
    a[0] = fl * u0[0];
    a[1] = fl * u1[0];
    #pragma unroll
    for (int q = 1; q < 6; ++q) {
        const int h = 1 << q;
        #pragma unroll
        for (int r = h - 1; r >= 0; --r) {
            const float base = a[r];
            a[r + h] = base * u1[q];
            a[r]     = base * u0[q];
        }
    }

    // ---- 4 variational layers
    #pragma unroll
    for (int layer = 0; layer < 4; ++layer) {

        // CNOT(0,1): ctrl reg bit0, tgt reg bit1 -> register rename (free)
        #pragma unroll
        for (int r = 0; r < 64; ++r)
            if ((r & 1) && !(r & 2)) { float t = a[r]; a[r] = a[r | 2]; a[r | 2] = t; }
        // CNOT(2,3)
        #pragma unroll
        for (int r = 0; r < 64; ++r)
            if ((r & 4) && !(r & 8)) { float t = a[r]; a[r] = a[r | 8]; a[r | 8] = t; }
        // CNOT(4,5)
        #pragma unroll
        for (int r = 0; r < 64; ++r)
            if ((r & 16) && !(r & 32)) { float t = a[r]; a[r] = a[r | 32]; a[r | 32] = t; }
        // CNOT(6,7): ctrl lane bit0, tgt lane bit1 -> one quad_perm (physical)
        #pragma unroll
        for (int r = 0; r < 64; ++r) a[r] = dppf<DPP_CNOT67>(a[r]);
        // CNOT(1,2)
        #pragma unroll
        for (int r = 0; r < 64; ++r)
            if ((r & 2) && !(r & 4)) { float t = a[r]; a[r] = a[r | 4]; a[r | 4] = t; }
        // CNOT(3,4)
        #pragma unroll
        for (int r = 0; r < 64; ++r)
            if ((r & 8) && !(r & 16)) { float t = a[r]; a[r] = a[r | 16]; a[r | 16] = t; }
        // CNOT(5,6): ctrl reg bit5, tgt lane bit0 -> quad_perm xor1 on regs 32..63
        #pragma unroll
        for (int r = 32; r < 64; ++r) a[r] = dppf<DPP_XOR1>(a[r]);

        // RY q0..q5, tan form: lo' = lo - t*hi ; hi' = hi + t*lo  (t in SGPR)
        #pragma unroll
        for (int q = 0; q < 6; ++q) {
            const float t = tl[layer * 8 + q];
            const int m = 1 << q;
            #pragma unroll
            for (int r = 0; r < 64; ++r) {
                if (!(r & m)) {
                    const float lo = a[r], hi = a[r | m];
                    a[r]     = fmaf(-t, hi, lo);
                    a[r | m] = fmaf( t, lo, hi);
                }
            }
        }
        // RY q6: partner across lane bit0; sign by lane bit0
        {
            const float t6 = tl[layer * 8 + 6];
            const float st = (k & 1) ? t6 : -t6;
            #pragma unroll
            for (int r = 0; r < 64; ++r)
                a[r] = fmaf(st, dppf<DPP_XOR1>(a[r]), a[r]);
        }
        // RY q7: partner across lane bit1; sign by lane bit1
        {
            const float t7 = tl[layer * 8 + 7];
            const float st = (k & 2) ? t7 : -t7;
            #pragma unroll
            for (int r = 0; r < 64; ++r)
                a[r] = fmaf(st, dppf<DPP_XOR2>(a[r]), a[r]);
        }
    }

    // ---- measurement: <Z_i> = C2 * sum_j (-1)^{bit_i(j)} amp_j^2
    #pragma unroll
    for (int r = 0; r < 64; ++r) a[r] = a[r] * a[r];

    float z[8];
    #pragma unroll
    for (int q = 0; q < 6; ++q) {
        const int n = 64 >> q;          // live prefix length of a[]
        float zz = 0.0f;
        #pragma unroll
        for (int i = 0; i < n / 2; ++i) {
            const float e = a[2 * i], o = a[2 * i + 1];
            zz  += e - o;
            a[i] = e + o;
        }
        z[q] = zz;
    }
    const float t = a[0];               // per-lane total probability

    // quad reductions (DPP): z0..z5 sum over 4 lanes
    #pragma unroll
    for (int q = 0; q < 6; ++q) {
        z[q] += dppf<DPP_XOR1>(z[q]);
        z[q] += dppf<DPP_XOR2>(z[q]);
    }
    // z6 = P(q6=0)-P(q6=1), z7 = P(q7=0)-P(q7=1)
    {
        const float v  = dppf<DPP_XOR1>(t);
        const float d6 = (k & 1) ? (v - t) : (t - v);
        z[6] = d6 + dppf<DPP_XOR2>(d6);
        const float wv = dppf<DPP_XOR2>(t);
        const float d7 = (k & 2) ? (wv - t) : (t - wv);
        z[7] = d7 + dppf<DPP_XOR1>(d7);
    }
    #pragma unroll
    for (int j = 0; j < 8; ++j) z[j] *= C2;

    // store: lane k of the quad writes out[8s+2k], out[8s+2k+1] (8B/lane, coalesced)
    const float lo = (k == 0) ? z[0] : (k == 1) ? z[2] : (k == 2) ? z[4] : z[6];
    const float hi = (k == 0) ? z[1] : (k == 1) ? z[3] : (k == 2) ? z[5] : z[7];
    *(float2*)(out + s * 8 + k * 2) = make_float2(lo, hi);
}

extern "C" void kernel_launch(void* const* d_in, const int* in_sizes, int n_in,
                              void* d_out, int out_size, void* d_ws, size_t ws_size,
                              hipStream_t stream) {
    const float* x = (const float*)d_in[0];
    const float* w = (const float*)d_in[1];
    float* out = (float*)d_out;
    const int B = in_sizes[0] / 8;                  // 131072 samples
    const int total_threads = B * 4;                // 4 lanes per sample
    const int blocks = (total_threads + 255) / 256;
    hipLaunchKernelGGL(vqc_kernel, dim3(blocks), dim3(256), 0, stream, x, w, out, B);
}